// Round 6
// baseline (455.117 us; speedup 1.0000x reference)
//
#include <hip/hip_runtime.h>

// Encoder: B=512, T=128, N=128, H=256
// Round 6: fix round-5 race (Q gets its own buffer — Q overlaid xw and raced
// across blocks); k_rnn barriers become raw lgkm-only s_barrier (xw prefetch
// loads / Q stores stay in flight across the per-step barrier; cross-wave
// visibility only needs LDS).
//  k_prep_w: Wxt[256][128], W2t[128][256], W1t[128][128], Wht[256][256] f16 [n][k]
//  k_gemm<K,MODE>: C = A @ Bt^T via mfma_f32_16x16x32_f16, Mt=64, Nt=128.
//  k_rnn : 32 blocks x 512 thr, 16 batches/block. h_{t+1} = tanh(xw_t + h_t@Wh)
//          via MFMA, Wh/W2 B-frags resident in VGPRs; h round-trips LDS f16;
//          Q[t] = exp2(C2L*(h_{t+1}@W2 + b2)) fused, lagged one iteration.
//  k_attn: e_i = sum_tau (-2wv)*rcp(P*Q+1) (+ softmax-invariant const, dropped)
//          pairwise rcp; softmax over i (no max needed); out = data*alpha.
// Workspace (f32 offsets): P 0 | xw 8388608 | Q 25165824 | wts(hf) 33554432
//   => 134,512,640 bytes.

#define C2L 2.8853900817779268f   // 2*log2(e)
#define L2E 1.4426950408889634f   // log2(e)

typedef _Float16 hf;
typedef _Float16 hf2 __attribute__((ext_vector_type(2)));
typedef _Float16 hf4 __attribute__((ext_vector_type(4)));
typedef _Float16 hf8 __attribute__((ext_vector_type(8)));
typedef float f32x4 __attribute__((ext_vector_type(4)));

__device__ __forceinline__ float fast_exp2(float x){
#if __has_builtin(__builtin_amdgcn_exp2f)
  return __builtin_amdgcn_exp2f(x);
#else
  return exp2f(x);
#endif
}
__device__ __forceinline__ float fast_rcp(float x){
#if __has_builtin(__builtin_amdgcn_rcpf)
  return __builtin_amdgcn_rcpf(x);
#else
  return 1.f/x;
#endif
}
// Block barrier that only drains LDS ops (NOT vmcnt) — keeps global prefetch
// loads / stores in flight across the barrier. Safe when cross-thread
// communication at the barrier is via LDS only.
__device__ __forceinline__ void sync_lds_only(){
  asm volatile("s_waitcnt lgkmcnt(0)" ::: "memory");
  __builtin_amdgcn_s_barrier();
}

// ---------------- weight prep: f32 [k][n] -> f16 [n][k] ----------------
__global__ __launch_bounds__(256) void k_prep_w(const float* __restrict__ Wx,
    const float* __restrict__ W2, const float* __restrict__ W1,
    const float* __restrict__ Wh, hf* __restrict__ wts){
  int tid = blockIdx.x*256 + threadIdx.x;   // 576 blocks -> 147456 threads
  if (tid < 32768){                          // Wxt[n<256][k<128]
    int n = tid >> 7, k = tid & 127;
    wts[tid] = (hf)Wx[k*256 + n];
  } else if (tid < 65536){                   // W2t[n<128][k<256]
    int t2 = tid - 32768;
    int n = t2 >> 8, k = t2 & 255;
    wts[tid] = (hf)W2[k*128 + n];
  } else if (tid < 81920){                   // W1t[n<128][k<128]
    int t3 = tid - 65536;
    int n = t3 >> 7, k = t3 & 127;
    wts[tid] = (hf)W1[k*256 - k*128 + n];    // placeholder avoided below
  } else {                                   // Wht[n<256][k<256]
    int t4 = tid - 81920;
    int n = t4 >> 8, k = t4 & 255;
    wts[tid] = (hf)Wh[k*256 + n];
  }
}

// (fixed W1 branch in a second tiny kernel to avoid the arithmetic typo above)
__global__ __launch_bounds__(256) void k_prep_w1(const float* __restrict__ W1,
    hf* __restrict__ W1t){
  int tid = blockIdx.x*256 + threadIdx.x;   // 64 blocks -> 16384 threads
  int n = tid >> 7, k = tid & 127;
  W1t[tid] = (hf)W1[k*128 + n];
}

// ---------------- unified MFMA GEMM (xw, pre) ----------------
// block = 256 thr (4 waves). Tile: M=64 (wave strip 16), N=128, K chunked by 128.
// LDS: As[64][136] + Bs[128][136] f16 = 52,224 B.
template<int K, int MODE>
__global__ __launch_bounds__(256) void k_gemm(const void* __restrict__ Asrc,
    const hf* __restrict__ Bt, const float* __restrict__ bias,
    float* __restrict__ Cout){
  constexpr int SA = 136;
  __shared__ alignas(16) hf As[64*SA];
  __shared__ alignas(16) hf Bs[128*SA];
  const int tid = threadIdx.x;
  const int w = tid >> 6, lane = tid & 63;
  const int c = lane & 15, q = lane >> 4;
  const int bx = blockIdx.x;
  const int col0 = (MODE==0) ? blockIdx.y*128 : 0;

  float br[8];
  #pragma unroll
  for (int ni=0; ni<8; ni++) br[ni] = bias[col0 + ni*16 + c];

  f32x4 acc[8];
  #pragma unroll
  for (int ni=0; ni<8; ni++) acc[ni] = (f32x4){0.f,0.f,0.f,0.f};

  for (int kc=0; kc<K/128; kc++){
    // ---- stage A chunk (64 rows x 128 k) ----
    if (MODE == 0){
      const float* A = (const float*)Asrc + (long)bx*64*128;
      #pragma unroll
      for (int v=0; v<8; v++){
        int f4 = v*256 + tid;
        int m = f4 >> 5, k4 = (f4 & 31)*4;
        float4 d = *(const float4*)&A[m*128 + k4];
        hf4 h = {(hf)d.x,(hf)d.y,(hf)d.z,(hf)d.w};
        *(hf4*)&As[m*SA + k4] = h;
      }
    } else {
      const float* A = (const float*)Asrc + (long)(bx>>1)*16384;
      const int i0 = (bx & 1)*64;
      #pragma unroll
      for (int v=0; v<8; v++){
        int f4 = v*256 + tid;
        int t = f4 >> 4, i4 = (f4 & 15)*4;
        float4 d = *(const float4*)&A[t*128 + i0 + i4];
        As[(i4+0)*SA + t] = (hf)d.x;
        As[(i4+1)*SA + t] = (hf)d.y;
        As[(i4+2)*SA + t] = (hf)d.z;
        As[(i4+3)*SA + t] = (hf)d.w;
      }
    }
    // ---- stage B chunk (128 n x 128 k), Bt is f16 [n][K] ----
    #pragma unroll
    for (int v=0; v<8; v++){
      int f8 = v*256 + tid;
      int n = f8 >> 4, k8 = (f8 & 15)*8;
      *(hf8*)&Bs[n*SA + k8] = *(const hf8*)&Bt[(col0+n)*K + kc*128 + k8];
    }
    __syncthreads();
    // ---- MFMA ----
    #pragma unroll
    for (int kk=0; kk<4; kk++){
      hf8 a = *(const hf8*)&As[(w*16 + c)*SA + kk*32 + q*8];
      #pragma unroll
      for (int ni=0; ni<8; ni++){
        hf8 b = *(const hf8*)&Bs[(ni*16 + c)*SA + kk*32 + q*8];
        acc[ni] = __builtin_amdgcn_mfma_f32_16x16x32_f16(a, b, acc[ni], 0, 0, 0);
      }
    }
    __syncthreads();
  }
  // ---- epilogue ----
  #pragma unroll
  for (int ni=0; ni<8; ni++){
    #pragma unroll
    for (int r=0; r<4; r++){
      int rloc = w*16 + q*4 + r;
      int col = col0 + ni*16 + c;
      float val = acc[ni][r] + br[ni];
      int addr;
      if (MODE == 0){
        int R = bx*64 + rloc;
        int b_ = R >> 7, t_ = R & 127;
        addr = (t_*512 + b_)*256 + col;
      } else {
        int b_ = bx >> 1, i_ = (bx & 1)*64 + rloc;
        addr = b_*16384 + i_*128 + col;
        val = fast_exp2(C2L*val);
      }
      Cout[addr] = val;
    }
  }
}

// ---------------- MFMA recurrence + fused Q ----------------
// grid 32 x 512 thr (8 waves). Block owns 16 batches (M=16 MFMA tile).
// Wave w: Wh cols j in [w*32, w*32+32) -> 16 B-frags; W2 rows tau in
// [w*16, w*16+16) -> 8 B-frags. Per iter: 8 ds_read_b128 A-frags (h_t) feed
// 16 Wh-MFMA + 8 W2-MFMA. h_{t+1} -> LDS f16. Q[t] computed at iter t+1.
// Barriers are lgkm-only: xw prefetch / Q stores stay in flight.
__global__ __launch_bounds__(512, 2) void k_rnn(const float* __restrict__ h0,
    const hf* __restrict__ Wht, const hf* __restrict__ W2t,
    const float* __restrict__ b2, const float* __restrict__ xw,
    float* __restrict__ Q){
  constexpr int SK = 264;                    // hf elements per h-row (pad)
  __shared__ alignas(16) hf hs[2][16*SK];    // 16,896 B
  const int tid = threadIdx.x;
  const int w = tid >> 6, lane = tid & 63;
  const int c = lane & 15, q = lane >> 4;
  const int bb0 = blockIdx.x*16;
  const int jb = w*32 + c;                   // Wh col base (ntl*16 offset)
  const int tau = w*16 + c;                  // W2 row

  // ---- resident weight fragments ----
  hf8 bf[2][8];                              // Wh: [ntl][kc]
  #pragma unroll
  for (int ntl=0; ntl<2; ntl++)
    #pragma unroll
    for (int kc=0; kc<8; kc++)
      bf[ntl][kc] = *(const hf8*)&Wht[(jb + ntl*16)*256 + kc*32 + q*8];
  hf8 wf[8];                                 // W2: [kc]
  #pragma unroll
  for (int kc=0; kc<8; kc++)
    wf[kc] = *(const hf8*)&W2t[tau*256 + kc*32 + q*8];
  const float b2v = b2[tau];

  // ---- stage h0 (16 x 256 f32 -> f16 LDS) ----
  {
    int m = tid >> 5, k0 = (tid & 31)*8;
    const float* src = h0 + (bb0 + m)*256 + k0;
    float4 u = *(const float4*)&src[0];
    float4 v = *(const float4*)&src[4];
    hf8 hh = {(hf)u.x,(hf)u.y,(hf)u.z,(hf)u.w,(hf)v.x,(hf)v.y,(hf)v.z,(hf)v.w};
    *(hf8*)&hs[0][m*SK + k0] = hh;
  }

  // ---- xw prefetch (t=0) ----
  float xwp[2][8];
  #pragma unroll
  for (int ntl=0; ntl<2; ntl++)
    #pragma unroll
    for (int r=0; r<4; r++)
      xwp[0][ntl*4+r] = xw[(bb0 + q*4 + r)*256 + jb + ntl*16];
  sync_lds_only();

  for (int t=0; t<=128; t++){
    const int cur = t & 1;
    // prefetch xw for t+1
    if (t < 128){
      int tp1 = (t < 127) ? t+1 : 0;
      #pragma unroll
      for (int ntl=0; ntl<2; ntl++)
        #pragma unroll
        for (int r=0; r<4; r++)
          xwp[cur^1][ntl*4+r] = xw[((tp1*512) + bb0 + q*4 + r)*256 + jb + ntl*16];
    }
    // A-frags + MFMA
    f32x4 acc0 = {0.f,0.f,0.f,0.f}, acc1 = {0.f,0.f,0.f,0.f};
    f32x4 qac  = {0.f,0.f,0.f,0.f};
    const hf* hrow = &hs[cur][0] + c*SK + q*8;
    #pragma unroll
    for (int kc=0; kc<8; kc++){
      hf8 af = *(const hf8*)(hrow + kc*32);
      if (t > 0)
        qac = __builtin_amdgcn_mfma_f32_16x16x32_f16(af, wf[kc], qac, 0,0,0);
      if (t < 128){
        acc0 = __builtin_amdgcn_mfma_f32_16x16x32_f16(af, bf[0][kc], acc0, 0,0,0);
        acc1 = __builtin_amdgcn_mfma_f32_16x16x32_f16(af, bf[1][kc], acc1, 0,0,0);
      }
    }
    // Q epilogue for step t-1 (uses h_t = hs[cur])
    if (t > 0){
      #pragma unroll
      for (int r=0; r<4; r++){
        float qv = fast_exp2(C2L*(qac[r] + b2v));
        Q[((t-1)*512 + bb0 + q*4 + r)*128 + tau] = qv;
      }
    }
    // recurrence epilogue: tanh -> hs[cur^1]
    if (t < 128){
      #pragma unroll
      for (int ntl=0; ntl<2; ntl++){
        f32x4 a = ntl ? acc1 : acc0;
        #pragma unroll
        for (int r=0; r<4; r++){
          float v = a[r] + xwp[cur][ntl*4+r];
          float e2 = fast_exp2(v*C2L);
          float hn = 1.f - 2.f*fast_rcp(e2 + 1.f);
          hs[cur^1][(q*4+r)*SK + jb + ntl*16] = (hf)hn;
        }
      }
    }
    sync_lds_only();
  }
}

// ---------------- attention + softmax + scale ----------------
// grid (512 b, 4 t-tiles), 256 threads. P row halves in registers (64 f32),
// Q tile (32 t) in LDS. Pairwise rcp: w0/u+w1/v = (w0 v + w1 u)*rcp(u*v)
// -> 1 rcp per 2 elements. 4 timesteps per sweep. No max in softmax
// (|e| <= sum|wv| ~ 5). 2 barriers per 4 timesteps (parity buffers).
__global__ __launch_bounds__(256, 4) void k_attn(const float* __restrict__ P,
    const float* __restrict__ Qm, const float* __restrict__ Wv,
    const float* __restrict__ data, float* __restrict__ out){
  __shared__ alignas(16) float qs[32*128];          // [tt][tau] 16KB
  __shared__ alignas(16) float wvs[128];
  __shared__ alignas(16) float epart[2][2][4][128]; // [parity][hl][tl][i] 16KB
  __shared__ float red[2][4][2];                    // [parity][tl][half]
  const int b = blockIdx.x, tile = blockIdx.y;
  const int tid = threadIdx.x;
  const int i = tid & 127, hl = tid >> 7;
  const int t0 = tile*32;
  if (tid < 128) wvs[tid] = -2.f*Wv[tid];
  #pragma unroll
  for (int v=0; v<4; v++){
    int flat = v*1024 + tid*4;
    int tt = flat >> 7, c = flat & 127;
    *(float4*)&qs[flat] = *(const float4*)&Qm[((t0+tt)*512 + b)*128 + c];
  }
  float4 p4[16];
  const float* prow = P + b*16384 + i*128 + hl*64;
  #pragma unroll
  for (int v=0; v<16; v++) p4[v] = *(const float4*)&prow[v*4];
  __syncthreads();
  for (int tp=0; tp<8; tp++){
    const int pp = tp & 1;
    const float* q0r = &qs[(4*tp)*128   + hl*64];
    const float* q1r = &qs[(4*tp+1)*128 + hl*64];
    const float* q2r = &qs[(4*tp+2)*128 + hl*64];
    const float* q3r = &qs[(4*tp+3)*128 + hl*64];
    const float* wvr = &wvs[hl*64];
    float acc0=0.f, acc1=0.f, acc2=0.f, acc3=0.f;
    #pragma unroll
    for (int m=0; m<16; m++){
      float4 Pv = p4[m];
      float4 wv = *(const float4*)&wvr[m*4];
      {
        float4 qq = *(const float4*)&q0r[m*4];
        float u = fmaf(Pv.x, qq.x, 1.f), v = fmaf(Pv.y, qq.y, 1.f);
        float n = fmaf(wv.x, v, wv.y*u);
        acc0 = fmaf(n, fast_rcp(u*v), acc0);
        float u2 = fmaf(Pv.z, qq.z, 1.f), v2 = fmaf(Pv.w, qq.w, 1.f);
        float n2 = fmaf(wv.z, v2, wv.w*u2);
        acc0 = fmaf(n2, fast_rcp(u2*v2), acc0);
      }
      {
        float4 qq = *(const float4*)&q1r[m*4];
        float u = fmaf(Pv.x, qq.x, 1.f), v = fmaf(Pv.y, qq.y, 1.f);
        float n = fmaf(wv.x, v, wv.y*u);
        acc1 = fmaf(n, fast_rcp(u*v), acc1);
        float u2 = fmaf(Pv.z, qq.z, 1.f), v2 = fmaf(Pv.w, qq.w, 1.f);
        float n2 = fmaf(wv.z, v2, wv.w*u2);
        acc1 = fmaf(n2, fast_rcp(u2*v2), acc1);
      }
      {
        float4 qq = *(const float4*)&q2r[m*4];
        float u = fmaf(Pv.x, qq.x, 1.f), v = fmaf(Pv.y, qq.y, 1.f);
        float n = fmaf(wv.x, v, wv.y*u);
        acc2 = fmaf(n, fast_rcp(u*v), acc2);
        float u2 = fmaf(Pv.z, qq.z, 1.f), v2 = fmaf(Pv.w, qq.w, 1.f);
        float n2 = fmaf(wv.z, v2, wv.w*u2);
        acc2 = fmaf(n2, fast_rcp(u2*v2), acc2);
      }
      {
        float4 qq = *(const float4*)&q3r[m*4];
        float u = fmaf(Pv.x, qq.x, 1.f), v = fmaf(Pv.y, qq.y, 1.f);
        float n = fmaf(wv.x, v, wv.y*u);
        acc3 = fmaf(n, fast_rcp(u*v), acc3);
        float u2 = fmaf(Pv.z, qq.z, 1.f), v2 = fmaf(Pv.w, qq.w, 1.f);
        float n2 = fmaf(wv.z, v2, wv.w*u2);
        acc3 = fmaf(n2, fast_rcp(u2*v2), acc3);
      }
    }
    epart[pp][hl][0][i] = acc0;
    epart[pp][hl][1][i] = acc1;
    epart[pp][hl][2][i] = acc2;
    epart[pp][hl][3][i] = acc3;
    __syncthreads();
    const int g = tid >> 7;    // 0/1
    float pe[2];
    #pragma unroll
    for (int s=0; s<2; s++){
      int tl = g + 2*s;        // g=0 -> t 0,2 ; g=1 -> t 1,3
      float e = epart[pp][0][tl][i] + epart[pp][1][tl][i];
      pe[s] = fast_exp2(e*L2E);
      float sm = pe[s];
      #pragma unroll
      for (int off=32; off; off>>=1) sm += __shfl_xor(sm, off);
      if ((tid & 63) == 0) red[pp][tl][(tid>>6)&1] = sm;
    }
    __syncthreads();
    #pragma unroll
    for (int s=0; s<2; s++){
      int tl = g + 2*s;
      float ssum = red[pp][tl][0] + red[pp][tl][1];
      float alpha = pe[s] * fast_rcp(ssum);
      int t = t0 + 4*tp + tl;
      int base = (t*512 + b)*128 + i;
      out[base] = data[base]*alpha;
    }
  }
}

extern "C" void kernel_launch(void* const* d_in, const int* in_sizes, int n_in,
                              void* d_out, int out_size, void* d_ws, size_t ws_size,
                              hipStream_t stream) {
  const float* data = (const float*)d_in[0];
  const float* h0   = (const float*)d_in[1];
  const float* Wx   = (const float*)d_in[2];
  const float* Wh   = (const float*)d_in[3];
  const float* bb   = (const float*)d_in[4];
  const float* W1   = (const float*)d_in[5];
  const float* b1   = (const float*)d_in[6];
  const float* W2   = (const float*)d_in[7];
  const float* b2   = (const float*)d_in[8];
  const float* Wv   = (const float*)d_in[9];
  // d_in[10] = bv: softmax-invariant constant, dropped. d_in[11] = n (128).
  float* wsp = (float*)d_ws;
  float* P    = wsp;                        //  8,388,608 f
  float* xw   = wsp + 8388608;              // 16,777,216 f
  float* Qbuf = wsp + 25165824;             //  8,388,608 f  (separate! no overlay)
  hf*    wts  = (hf*)(wsp + 33554432);      // 147,456 hf
  hf*    Wxt  = wts;                        // [256][128]
  hf*    W2t  = wts + 32768;                // [128][256]
  hf*    W1t  = wts + 65536;                // [128][128]
  hf*    Wht  = wts + 81920;                // [256][256]
  float* out = (float*)d_out;

  hipLaunchKernelGGL(k_prep_w, dim3(576), dim3(256), 0, stream, Wx, W2, W1, Wh, wts);
  hipLaunchKernelGGL(k_prep_w1, dim3(64), dim3(256), 0, stream, W1, W1t);
  hipLaunchKernelGGL((k_gemm<128,0>), dim3(1024,2), dim3(256), 0, stream,
                     (const void*)data, Wxt, bb, xw);
  hipLaunchKernelGGL((k_gemm<128,2>), dim3(1024),   dim3(256), 0, stream,
                     (const void*)data, W1t, b1, P);
  hipLaunchKernelGGL(k_rnn, dim3(32), dim3(512), 0, stream,
                     h0, Wht, W2t, b2, xw, Qbuf);
  hipLaunchKernelGGL(k_attn, dim3(512, 4), dim3(256), 0, stream, P, Qbuf, Wv, data, out);
}